// Round 9
// baseline (212.436 us; speedup 1.0000x reference)
//
#include <hip/hip_runtime.h>
#include <stdint.h>
#include <stddef.h>

// Problem constants (B=2, S=2048, D=2048, H=16, KVH=4, HD=128)
#define S_LEN  2048
#define NH     16
#define NKVH   4
#define HD_    128
#define DMODEL 2048
#define NQKV   3072      // H*HD + 2*KVH*HD
#define MROWS  4096      // B*S

typedef __attribute__((ext_vector_type(8)))  __bf16 bf16x8;
typedef __attribute__((ext_vector_type(4)))  __bf16 bf16x4;
typedef __attribute__((ext_vector_type(4)))  float  f32x4;
typedef __attribute__((ext_vector_type(16))) float  f32x16;

#define MFMA16(a, b, c) __builtin_amdgcn_mfma_f32_16x16x32_bf16((a), (b), (c), 0, 0, 0)
#define MFMA32(a, b, c) __builtin_amdgcn_mfma_f32_32x32x16_bf16((a), (b), (c), 0, 0, 0)

__device__ __forceinline__ void gload16(const void* g, void* l) {
  __builtin_amdgcn_global_load_lds((const __attribute__((address_space(1))) void*)g,
                                   (__attribute__((address_space(3))) void*)l,
                                   16, 0, 0);
}

// packed f32x2 -> bf16x2 (no builtin on gfx950; guide T12)
__device__ __forceinline__ uint32_t cvtpk(float lo, float hi) {
  uint32_t d;
  asm("v_cvt_pk_bf16_f32 %0, %1, %2" : "=v"(d) : "v"(lo), "v"(hi));
  return d;
}
// v_permlane32_swap_b32: a[32:63] <-> b[0:31].  s_nop guards the
// VALU-write -> permlane cross-lane-read hazard across asm blocks.
// a and b MUST be distinct SSA values (round-2 bug).
__device__ __forceinline__ void pswap(uint32_t& a, uint32_t& b) {
  asm("s_nop 1\n\tv_permlane32_swap_b32 %0, %1" : "+v"(a), "+v"(b));
}
// raw v_exp_f32 (= 2^x); OCML exp2f's guarded path was the r4 VALU hit.
__device__ __forceinline__ float fast_exp2(float x) {
  float r;
  asm("v_exp_f32 %0, %1\n\ts_nop 0" : "=v"(r) : "v"(x));
  return r;
}
__device__ __forceinline__ float bf2f(uint16_t u) {
  uint32_t x = ((uint32_t)u) << 16;
  return __builtin_bit_cast(float, x);
}
__device__ __forceinline__ uint16_t f2bf(float f) {
  uint32_t u = __builtin_bit_cast(uint32_t, f);
  uint32_t r = (u + 0x7FFFu + ((u >> 16) & 1u)) >> 16;
  return (uint16_t)r;
}

// ---------------------------------------------------------------------------
// 1) prep: blocks [0,8192): x f32 -> xb bf16 (float4 each thread)
//          blocks [8192,10752): 64x64 LDS-tiled transpose of wq/wk/wv/wo
//          into bf16 [N][K] layouts.
// ---------------------------------------------------------------------------
__global__ void prep_kernel(const float* __restrict__ x, __bf16* __restrict__ xb,
                            const float* __restrict__ wq, const float* __restrict__ wk,
                            const float* __restrict__ wv, const float* __restrict__ wo,
                            __bf16* __restrict__ wqkvT, __bf16* __restrict__ woT) {
  __shared__ float tile[64][65];
  const int bid = blockIdx.x;
  const int tid = threadIdx.x;
  if (bid < 8192) {
    size_t i = (size_t)bid * 256 + tid;
    const float4* xv = (const float4*)x;
    float4 v = xv[i];
    bf16x4 o;
    o[0] = (__bf16)v.x; o[1] = (__bf16)v.y; o[2] = (__bf16)v.z; o[3] = (__bf16)v.w;
    *(bf16x4*)(xb + i * 4) = o;
    return;
  }
  int b2 = bid - 8192;
  const float* W; __bf16* WT; int ldw, kx, ny;
  if (b2 < 1024)      { W = wq; WT = wqkvT;                        ldw = 2048; kx = b2 & 31; ny = b2 >> 5; }
  else if (b2 < 1280) { int t = b2 - 1024; W = wk; WT = wqkvT + (size_t)2048 * 2048; ldw = 512; kx = t & 31; ny = t >> 5; }
  else if (b2 < 1536) { int t = b2 - 1280; W = wv; WT = wqkvT + (size_t)2560 * 2048; ldw = 512; kx = t & 31; ny = t >> 5; }
  else                { int t = b2 - 1536; W = wo; WT = woT;       ldw = 2048; kx = t & 31; ny = t >> 5; }
  const int k0 = kx * 64, n0 = ny * 64;
#pragma unroll
  for (int r = 0; r < 16; ++r) {
    int idx = r * 256 + tid;
    int kr = idx >> 6, nc = idx & 63;
    tile[kr][nc] = W[(size_t)(k0 + kr) * ldw + n0 + nc];
  }
  __syncthreads();
#pragma unroll
  for (int r = 0; r < 16; ++r) {
    int idx = r * 256 + tid;
    int nr = idx >> 6, kc = idx & 63;
    WT[(size_t)(n0 + nr) * 2048 + k0 + kc] = (__bf16)tile[kc][nr];
  }
}

// ---------------------------------------------------------------------------
// 2/5) bf16 GEMM: C[M][N] = A[M][K] * Bt[N][K]^T.  128x128 tile, BK=64,
// 4 waves (2x2), 4x4 16x16x32 frags/wave, swizzled global_load_lds staging,
// XCD-aware block swizzle (bijective: both grids divisible by 8).
// MODE 0: plain f32 C store (output projection).
// MODE 1: QKV epilogue — RoPE on Q (scaled log2(e)/sqrt(HD), for exp2-domain
//   softmax) -> xq row-major; RoPE on K -> Kp PANEL layout; V -> VTp panels.
//   Kp:  [bkv][kt][c2=d/8 (16)][r (64)][8]   (K[s][d], s=kt*64+r)
//   VTp: [bkv][kt][c2=s/8 (8)][d (128)][8]   (V[s][d] transposed)
// ---------------------------------------------------------------------------
template <int MODE>
__global__ __launch_bounds__(256, 2) void gemm_kernel(
    const __bf16* __restrict__ A, int lda,
    const __bf16* __restrict__ Bt, int ldb,
    void* __restrict__ Cout, int ldc, int Kdim,
    const float* __restrict__ fc, const float* __restrict__ fs,
    __bf16* __restrict__ xq, __bf16* __restrict__ Kp, __bf16* __restrict__ VTp) {
  __shared__ __attribute__((aligned(16))) __bf16 As[128 * 64];
  __shared__ __attribute__((aligned(16))) __bf16 Bs[128 * 64];
  const int tid = threadIdx.x;
  const int w = tid >> 6, l = tid & 63, lg = l >> 4, lr = l & 15;
  const int wm = w >> 1, wn = w & 1;

  // T1 XCD swizzle (bijective: nwg divisible by 8)
  const int nwg = gridDim.x * gridDim.y;
  const int lid = blockIdx.y * gridDim.x + blockIdx.x;
  const int swz = (lid & 7) * (nwg >> 3) + (lid >> 3);
  const int bx = swz % gridDim.x, by = swz / gridDim.x;
  const int m0 = by * 128, n0 = bx * 128;

  f32x4 acc[4][4] = {};

  for (int k0 = 0; k0 < Kdim; k0 += 64) {
#pragma unroll
    for (int t = 0; t < 4; ++t) {
      int o = (t * 256 + tid) * 16;       // linear byte offset in 16KB tile
      int row = o >> 7;                   // 128B rows (64 bf16)
      int slot = (o >> 4) & 7;
      int sw = slot ^ (row & 7);          // involution: pre-swizzled source
      gload16(A + (size_t)(m0 + row) * lda + k0 + sw * 8,
              (char*)As + t * 4096 + (w << 10));
      gload16(Bt + (size_t)(n0 + row) * ldb + k0 + sw * 8,
              (char*)Bs + t * 4096 + (w << 10));
    }
    __syncthreads();
#pragma unroll
    for (int c = 0; c < 2; ++c) {
      bf16x8 af[4];
#pragma unroll
      for (int mi = 0; mi < 4; ++mi) {
        int row = wm * 64 + mi * 16 + lr;
        int slot = (c * 4 + lg) ^ (row & 7);
        af[mi] = *(const bf16x8*)((const char*)As + row * 128 + slot * 16);
      }
#pragma unroll
      for (int ni = 0; ni < 4; ++ni) {
        int rn = wn * 64 + ni * 16 + lr;
        int slot = (c * 4 + lg) ^ (rn & 7);
        bf16x8 bfr = *(const bf16x8*)((const char*)Bs + rn * 128 + slot * 16);
#pragma unroll
        for (int mi = 0; mi < 4; ++mi)
          acc[mi][ni] = MFMA16(af[mi], bfr, acc[mi][ni]);
      }
    }
    __syncthreads();
  }

  if (MODE == 1) {
    const float qs = 0.12755102871936672f;   // log2(e)/sqrt(128)
    if (n0 < 2560) {
      // Q or K range (block-uniform since n0 is a multiple of 128)
#pragma unroll
      for (int mi = 0; mi < 4; ++mi)
#pragma unroll
        for (int ni = 0; ni < 4; ++ni)
#pragma unroll
          for (int i = 0; i < 4; ++i) {
            float v = acc[mi][ni][i];
            float p = __shfl_xor(v, 1);      // partner of the (xr,xi) pair
            int cc = n0 + wn * 64 + ni * 16 + lr;
            int r  = m0 + wm * 64 + mi * 16 + lg * 4 + i;
            int s  = r & (S_LEN - 1);
            int j  = (cc & 127) >> 1;
            float c = fc[s * 64 + j], sn = fs[s * 64 + j];
            float o = (lr & 1) ? (p * sn + v * c)
                               : (v * c - p * sn);
            if (n0 < DMODEL) {               // Q -> xq row-major, scaled
              xq[(size_t)r * DMODEL + cc] = (__bf16)(o * qs);
            } else {                         // K -> Kp panels
              int bb = r >> 11, kt = s >> 6, rr = s & 63;
              int kvh = (cc - DMODEL) >> 7, dk = (cc - DMODEL) & 127;
              size_t e = ((size_t)((bb * 4 + kvh) * 32 + kt) * 16 + (dk >> 3)) * 512
                         + rr * 8 + (dk & 7);
              Kp[e] = (__bf16)o;
            }
          }
    } else {
      // V range -> VTp panels (no RoPE)
#pragma unroll
      for (int mi = 0; mi < 4; ++mi)
#pragma unroll
        for (int ni = 0; ni < 4; ++ni)
#pragma unroll
          for (int i = 0; i < 4; ++i) {
            float v = acc[mi][ni][i];
            int cc = n0 + wn * 64 + ni * 16 + lr;
            int r  = m0 + wm * 64 + mi * 16 + lg * 4 + i;
            int s  = r & (S_LEN - 1);
            int bb = r >> 11, kt = s >> 6, rr = s & 63;
            int kvh = (cc - 2560) >> 7, d = (cc - 2560) & 127;
            size_t e = ((size_t)((bb * 4 + kvh) * 32 + kt) * 8 + (rr >> 3)) * 1024
                       + d * 8 + (rr & 7);
            VTp[e] = (__bf16)v;
          }
    }
    return;
  }

#pragma unroll
  for (int mi = 0; mi < 4; ++mi)
#pragma unroll
    for (int ni = 0; ni < 4; ++ni)
#pragma unroll
      for (int i = 0; i < 4; ++i) {
        int r = m0 + wm * 64 + mi * 16 + lg * 4 + i;
        int cc = n0 + wn * 64 + ni * 16 + lr;
        ((float*)Cout)[(size_t)r * ldc + cc] = acc[mi][ni][i];
      }
}

// ---------------------------------------------------------------------------
// 3) Flash attention — KV-SPLIT 2x (blockIdx.z = half): each block scans 16
// of 32 kv-tiles and writes a NORMALIZED bf16 partial O plus per-row (m,l).
// Single 32KB K/V buffer (4 blocks/CU -> 4 waves/SIMD; the per-tile load
// stall now hides under the other 3 resident waves' compute).  Core
// tile_step identical to the verified r6 kernel.
// ---------------------------------------------------------------------------
__global__ __launch_bounds__(256, 2) void attn_kernel(
    const __bf16* __restrict__ xq, const __bf16* __restrict__ Kp,
    const __bf16* __restrict__ VTp, __bf16* __restrict__ out0,
    __bf16* __restrict__ out1, float2* __restrict__ ml) {
  __shared__ __attribute__((aligned(16))) __bf16 Ks[64 * 128];
  __shared__ __attribute__((aligned(16))) __bf16 Vs[128 * 64];
  const int tid = threadIdx.x;
  const int w = tid >> 6, l = tid & 63;
  const int qc = l & 31, hi = l >> 5;
  const int bh = blockIdx.y;             // 0..31
  const int half = blockIdx.z;           // 0..1 (kv half)
  const int b = bh >> 4, h = bh & 15, kvh = h >> 2;
  const int bkv = b * NKVH + kvh;
  const int q0 = blockIdx.x * 128 + w * 32;   // wave's first q row within S
  const int kt0 = half * 16;

  const __bf16* Ktiles = Kp  + (size_t)bkv * 32 * 8192;   // + kt*8192 elems
  const __bf16* Vtiles = VTp + (size_t)bkv * 32 * 8192;

  // stage one 16KB K tile + one 16KB V tile (linear copy, coalesced)
  auto stage = [&](int kt) {
    const __bf16* ksrc = Ktiles + (size_t)kt * 8192;
    const __bf16* vsrc = Vtiles + (size_t)kt * 8192;
#pragma unroll
    for (int t = 0; t < 4; ++t) {
      gload16(ksrc + (t * 256 + tid) * 8, (char*)Ks + t * 4096 + (w << 10));
      gload16(vsrc + (t * 256 + tid) * 8, (char*)Vs + t * 4096 + (w << 10));
    }
  };

  // Q fragments (B-operand): lane holds Q[q0+qc][d = c*16 + hi*8 + j]
  bf16x8 aq[8];
#pragma unroll
  for (int c = 0; c < 8; ++c)
    aq[c] = *(const bf16x8*)(xq + (size_t)(b * S_LEN + q0 + qc) * DMODEL +
                             h * HD_ + c * 16 + hi * 8);

  f32x16 o_acc[4] = {};                  // O^T: rows d = 32dt + crow(r,hi), col q
  float m = -1e30f, lsum = 0.0f;

  typedef union { uint32_t u[4]; bf16x8 v; } pfrag_t;

  // one kv-tile's compute (QK^T -> online softmax -> P-pack -> PV)
  auto tile_step = [&]() {
    const char* kb = (const char*)Ks + hi * 1024 + qc * 16;
    const char* vb = (const char*)Vs + hi * 2048 + qc * 16;

    // ---- swapped QK^T: st[t] = S^T[kv = 32t + crow(r,hi)][q = qc] (log2-dom)
    f32x16 st[2] = {};
    __builtin_amdgcn_s_setprio(1);
#pragma unroll
    for (int t = 0; t < 2; ++t) {
#pragma unroll
      for (int c = 0; c < 8; ++c) {
        bf16x8 kf = *(const bf16x8*)(kb + c * 2048 + t * 512);
        st[t] = MFMA32(kf, aq[c], st[t]);
      }
    }
    __builtin_amdgcn_s_setprio(0);

    // ---- in-register softmax (lane owns one q row; pair lane = other half)
    float pm = st[0][0];
#pragma unroll
    for (int t = 0; t < 2; ++t)
#pragma unroll
      for (int r = 0; r < 16; ++r) pm = fmaxf(pm, st[t][r]);
    pm = fmaxf(pm, __shfl_xor(pm, 32));

    if (__any(pm - m > 11.54f)) {        // defer-max (T13), 8*log2(e)
      float mn = fmaxf(m, pm);
      float sf = fast_exp2(m - mn);
      lsum *= sf;
#pragma unroll
      for (int dt = 0; dt < 4; ++dt)
#pragma unroll
        for (int r = 0; r < 16; ++r) o_acc[dt][r] *= sf;
      m = mn;
    }

    float rsum = 0.0f;
#pragma unroll
    for (int t = 0; t < 2; ++t)
#pragma unroll
      for (int r = 0; r < 16; ++r) {
        st[t][r] = fast_exp2(st[t][r] - m);
        rsum += st[t][r];
      }
    rsum += __shfl_xor(rsum, 32);
    lsum += rsum;

    // ---- pack P -> bf16 PV fragments (cvt_pk + permlane32_swap, T12)
    pfrag_t pf[4];
#pragma unroll
    for (int t = 0; t < 2; ++t)
#pragma unroll
      for (int half2 = 0; half2 < 2; ++half2) {
        int bs = half2 * 8;
        uint32_t x0 = cvtpk(st[t][bs + 0], st[t][bs + 1]);
        uint32_t y0 = cvtpk(st[t][bs + 4], st[t][bs + 5]);
        uint32_t x1 = cvtpk(st[t][bs + 2], st[t][bs + 3]);
        uint32_t y1 = cvtpk(st[t][bs + 6], st[t][bs + 7]);
        pswap(x0, y0);
        pswap(x1, y1);
        pf[t * 2 + half2].u[0] = x0;
        pf[t * 2 + half2].u[1] = x1;
        pf[t * 2 + half2].u[2] = y0;
        pf[t * 2 + half2].u[3] = y1;
      }

    // ---- PV transposed: O^T += mfma32(V^T_frag, P^T_frag)
    __builtin_amdgcn_s_setprio(1);
#pragma unroll
    for (int dt = 0; dt < 4; ++dt) {
#pragma unroll
      for (int ks = 0; ks < 4; ++ks) {
        bf16x8 vf = *(const bf16x8*)(vb + ks * 4096 + dt * 512);
        o_acc[dt] = MFMA32(vf, pf[ks].v, o_acc[dt]);
      }
    }
    __builtin_amdgcn_s_setprio(0);
  };

#pragma unroll 1
  for (int t = 0; t < 16; ++t) {
    stage(kt0 + t);
    __syncthreads();                     // loads drained, tile ready
    tile_step();
    __syncthreads();                     // all waves done before overwrite
  }

  // ---- epilogue: normalize partial, write bf16 + (m, l) per q-row
  __bf16* outp = half ? out1 : out0;
  float rinv = 1.0f / lsum;
  const int row = b * S_LEN + q0 + qc;
  const size_t orow = (size_t)row * DMODEL + h * HD_;
#pragma unroll
  for (int dt = 0; dt < 4; ++dt)
#pragma unroll
    for (int rg = 0; rg < 4; ++rg) {
      bf16x4 ov;
#pragma unroll
      for (int i = 0; i < 4; ++i)
        ov[i] = (__bf16)(o_acc[dt][rg * 4 + i] * rinv);
      int d = dt * 32 + rg * 8 + hi * 4;   // crow(rg*4+i,hi) = i + 8rg + 4hi
      *(bf16x4*)(outp + orow + d) = ov;
    }
  if (hi == 0) {
    float2 v; v.x = m; v.y = lsum;
    ml[(size_t)half * (MROWS * NH) + (size_t)row * NH + h] = v;
  }
}

// ---------------------------------------------------------------------------
// 4) Combine the two KV-half partials: out = (w0*O0 + w1*O1)/(w0+w1),
// w_h = exp2(m_h - M) * l_h (log2-domain m).  One wave per (row, head);
// lane handles 2 cols (one u32).  In-place into out0 (= xb).
// ---------------------------------------------------------------------------
__global__ void combine_kernel(__bf16* __restrict__ out0,
                               const __bf16* __restrict__ out1,
                               const float2* __restrict__ ml) {
  const int tid = threadIdx.x;
  const int unit = blockIdx.x * 4 + (tid >> 6);   // (row, h) index, 0..65535
  const int lane = tid & 63;
  const int row = unit >> 4, h = unit & 15;
  float2 ml0 = ml[(size_t)row * NH + h];
  float2 ml1 = ml[(size_t)(MROWS * NH) + (size_t)row * NH + h];
  float M = fmaxf(ml0.x, ml1.x);
  float w0 = fast_exp2(ml0.x - M) * ml0.y;
  float w1 = fast_exp2(ml1.x - M) * ml1.y;
  float inv = 1.0f / (w0 + w1);
  w0 *= inv; w1 *= inv;
  size_t e = (size_t)row * DMODEL + h * HD_ + lane * 2;
  uint32_t a = *(const uint32_t*)(out0 + e);
  uint32_t c = *(const uint32_t*)(out1 + e);
  float lo = w0 * bf2f((uint16_t)(a & 0xFFFFu)) + w1 * bf2f((uint16_t)(c & 0xFFFFu));
  float hi2 = w0 * bf2f((uint16_t)(a >> 16)) + w1 * bf2f((uint16_t)(c >> 16));
  uint32_t r = (uint32_t)f2bf(lo) | ((uint32_t)f2bf(hi2) << 16);
  *(uint32_t*)(out0 + e) = r;
}

// ---------------------------------------------------------------------------
extern "C" void kernel_launch(void* const* d_in, const int* in_sizes, int n_in,
                              void* d_out, int out_size, void* d_ws, size_t ws_size,
                              hipStream_t stream) {
  const float* x  = (const float*)d_in[0];
  const float* fc = (const float*)d_in[1];
  const float* fs = (const float*)d_in[2];
  const float* wq = (const float*)d_in[3];
  const float* wk = (const float*)d_in[4];
  const float* wv = (const float*)d_in[5];
  const float* wo = (const float*)d_in[6];
  // d_in[7]/d_in[8] caches unused (start_pos==0, s==S), d_in[9] start_pos==0.

  char* ws = (char*)d_ws;
  __bf16* xb    = (__bf16*)(ws);                 // 16 MiB: x bf16; later O0 / attn-out
  __bf16* wqkvT = (__bf16*)(ws + (16u << 20));   // 12 MiB: [3072][2048]
  __bf16* woT   = (__bf16*)(ws + (28u << 20));   //  8 MiB: [2048][2048]
  __bf16* xq    = (__bf16*)(ws + (36u << 20));   // 16 MiB: Q post-rope [4096][2048]
  __bf16* Kp    = (__bf16*)(ws + (52u << 20));   //  4 MiB: K panels
  __bf16* VTp   = (__bf16*)(ws + (56u << 20));   //  4 MiB: V^T panels
  // d_out (33.5 MiB f32) doubles as scratch until gemm2 overwrites it:
  __bf16* o1 = (__bf16*)d_out;                          // 16 MiB: O1 partial
  float2* ml = (float2*)((char*)d_out + (16u << 20));   //  1 MiB: (m,l) x 2 halves

  // 1) x->bf16 + all weight transposes (one launch)
  prep_kernel<<<10752, 256, 0, stream>>>(x, xb, wq, wk, wv, wo, wqkvT, woT);
  // 2) fused QKV projection + RoPE + panel scatter -> xq / Kp / VTp
  {
    dim3 g(NQKV / 128, MROWS / 128);     // 768 blocks (768 % 8 == 0)
    gemm_kernel<1><<<g, 256, 0, stream>>>(xb, 2048, wqkvT, 2048, nullptr, 0, 2048,
                                          fc, fs, xq, Kp, VTp);
  }
  // 3) flash attention, KV-split 2x -> partials in xb (half 0) and o1 (half 1)
  {
    dim3 g(S_LEN / 128, 32, 2);          // 1024 blocks
    attn_kernel<<<g, 256, 0, stream>>>(xq, Kp, VTp, xb, o1, ml);
  }
  // 4) combine partials in place -> xb = attn-out bf16 [4096][2048]
  combine_kernel<<<16384, 256, 0, stream>>>(xb, o1, ml);
  // 5) output projection -> d_out f32 (overwrites the scratch)
  {
    dim3 g(DMODEL / 128, MROWS / 128);   // 512 blocks (512 % 8 == 0)
    gemm_kernel<0><<<g, 256, 0, stream>>>(xb, 2048, woT, 2048, d_out, 2048, 2048,
                                          fc, fs, nullptr, nullptr, nullptr);
  }
}

// Round 10
// 193.974 us; speedup vs baseline: 1.0952x; 1.0952x over previous
//
#include <hip/hip_runtime.h>
#include <stdint.h>
#include <stddef.h>

// Problem constants (B=2, S=2048, D=2048, H=16, KVH=4, HD=128)
#define S_LEN  2048
#define NH     16
#define NKVH   4
#define HD_    128
#define DMODEL 2048
#define NQKV   3072      // H*HD + 2*KVH*HD
#define MROWS  4096      // B*S

typedef __attribute__((ext_vector_type(8)))  __bf16 bf16x8;
typedef __attribute__((ext_vector_type(4)))  __bf16 bf16x4;
typedef __attribute__((ext_vector_type(4)))  float  f32x4;
typedef __attribute__((ext_vector_type(16))) float  f32x16;

#define MFMA16(a, b, c) __builtin_amdgcn_mfma_f32_16x16x32_bf16((a), (b), (c), 0, 0, 0)
#define MFMA32(a, b, c) __builtin_amdgcn_mfma_f32_32x32x16_bf16((a), (b), (c), 0, 0, 0)

__device__ __forceinline__ void gload16(const void* g, void* l) {
  __builtin_amdgcn_global_load_lds((const __attribute__((address_space(1))) void*)g,
                                   (__attribute__((address_space(3))) void*)l,
                                   16, 0, 0);
}

// packed f32x2 -> bf16x2 (no builtin on gfx950; guide T12)
__device__ __forceinline__ uint32_t cvtpk(float lo, float hi) {
  uint32_t d;
  asm("v_cvt_pk_bf16_f32 %0, %1, %2" : "=v"(d) : "v"(lo), "v"(hi));
  return d;
}
// v_permlane32_swap_b32: a[32:63] <-> b[0:31].  s_nop guards the
// VALU-write -> permlane cross-lane-read hazard across asm blocks.
// a and b MUST be distinct SSA values (round-2 bug).
__device__ __forceinline__ void pswap(uint32_t& a, uint32_t& b) {
  asm("s_nop 1\n\tv_permlane32_swap_b32 %0, %1" : "+v"(a), "+v"(b));
}
// raw v_exp_f32 (= 2^x); OCML exp2f's guarded path was the r4 VALU hit.
__device__ __forceinline__ float fast_exp2(float x) {
  float r;
  asm("v_exp_f32 %0, %1\n\ts_nop 0" : "=v"(r) : "v"(x));
  return r;
}

// ---------------------------------------------------------------------------
// 1) prep: blocks [0,8192): x f32 -> xb bf16 (float4 each thread)
//          blocks [8192,10752): 64x64 LDS-tiled transpose of wq/wk/wv/wo
//          into bf16 [N][K] layouts.
// ---------------------------------------------------------------------------
__global__ void prep_kernel(const float* __restrict__ x, __bf16* __restrict__ xb,
                            const float* __restrict__ wq, const float* __restrict__ wk,
                            const float* __restrict__ wv, const float* __restrict__ wo,
                            __bf16* __restrict__ wqkvT, __bf16* __restrict__ woT) {
  __shared__ float tile[64][65];
  const int bid = blockIdx.x;
  const int tid = threadIdx.x;
  if (bid < 8192) {
    size_t i = (size_t)bid * 256 + tid;
    const float4* xv = (const float4*)x;
    float4 v = xv[i];
    bf16x4 o;
    o[0] = (__bf16)v.x; o[1] = (__bf16)v.y; o[2] = (__bf16)v.z; o[3] = (__bf16)v.w;
    *(bf16x4*)(xb + i * 4) = o;
    return;
  }
  int b2 = bid - 8192;
  const float* W; __bf16* WT; int ldw, kx, ny;
  if (b2 < 1024)      { W = wq; WT = wqkvT;                        ldw = 2048; kx = b2 & 31; ny = b2 >> 5; }
  else if (b2 < 1280) { int t = b2 - 1024; W = wk; WT = wqkvT + (size_t)2048 * 2048; ldw = 512; kx = t & 31; ny = t >> 5; }
  else if (b2 < 1536) { int t = b2 - 1280; W = wv; WT = wqkvT + (size_t)2560 * 2048; ldw = 512; kx = t & 31; ny = t >> 5; }
  else                { int t = b2 - 1536; W = wo; WT = woT;       ldw = 2048; kx = t & 31; ny = t >> 5; }
  const int k0 = kx * 64, n0 = ny * 64;
#pragma unroll
  for (int r = 0; r < 16; ++r) {
    int idx = r * 256 + tid;
    int kr = idx >> 6, nc = idx & 63;
    tile[kr][nc] = W[(size_t)(k0 + kr) * ldw + n0 + nc];
  }
  __syncthreads();
#pragma unroll
  for (int r = 0; r < 16; ++r) {
    int idx = r * 256 + tid;
    int nr = idx >> 6, kc = idx & 63;
    WT[(size_t)(n0 + nr) * 2048 + k0 + kc] = (__bf16)tile[kc][nr];
  }
}

// ---------------------------------------------------------------------------
// 2/4) bf16 GEMM: C[M][N] = A[M][K] * Bt[N][K]^T.  128x128 tile, BK=64,
// 4 waves (2x2), 4x4 16x16x32 frags/wave, swizzled global_load_lds staging.
// XCD-aware block swizzle (T1): bijective since both grids divide 8.
// MODE 0: plain f32 C store (output projection).
// MODE 1: QKV epilogue — RoPE on Q (scaled log2(e)/sqrt(HD), for exp2-domain
//   softmax) -> xq row-major; RoPE on K -> Kp PANEL layout; V -> VTp panels.
//   Kp:  [bkv][kt][c2=d/8 (16)][r (64)][8]   (K[s][d], s=kt*64+r)
//   VTp: [bkv][kt][c2=s/8 (8)][d (128)][8]   (V[s][d] transposed)
// ---------------------------------------------------------------------------
template <int MODE>
__global__ __launch_bounds__(256, 2) void gemm_kernel(
    const __bf16* __restrict__ A, int lda,
    const __bf16* __restrict__ Bt, int ldb,
    void* __restrict__ Cout, int ldc, int Kdim,
    const float* __restrict__ fc, const float* __restrict__ fs,
    __bf16* __restrict__ xq, __bf16* __restrict__ Kp, __bf16* __restrict__ VTp) {
  __shared__ __attribute__((aligned(16))) __bf16 As[128 * 64];
  __shared__ __attribute__((aligned(16))) __bf16 Bs[128 * 64];
  const int tid = threadIdx.x;
  const int w = tid >> 6, l = tid & 63, lg = l >> 4, lr = l & 15;
  const int wm = w >> 1, wn = w & 1;

  // T1 XCD swizzle (bijective: nwg divisible by 8)
  const int nwg = gridDim.x * gridDim.y;
  const int lid = blockIdx.y * gridDim.x + blockIdx.x;
  const int swz = (lid & 7) * (nwg >> 3) + (lid >> 3);
  const int bx = swz % gridDim.x, by = swz / gridDim.x;
  const int m0 = by * 128, n0 = bx * 128;

  f32x4 acc[4][4] = {};

  for (int k0 = 0; k0 < Kdim; k0 += 64) {
#pragma unroll
    for (int t = 0; t < 4; ++t) {
      int o = (t * 256 + tid) * 16;       // linear byte offset in 16KB tile
      int row = o >> 7;                   // 128B rows (64 bf16)
      int slot = (o >> 4) & 7;
      int sw = slot ^ (row & 7);          // involution: pre-swizzled source
      gload16(A + (size_t)(m0 + row) * lda + k0 + sw * 8,
              (char*)As + t * 4096 + (w << 10));
      gload16(Bt + (size_t)(n0 + row) * ldb + k0 + sw * 8,
              (char*)Bs + t * 4096 + (w << 10));
    }
    __syncthreads();
#pragma unroll
    for (int c = 0; c < 2; ++c) {
      bf16x8 af[4];
#pragma unroll
      for (int mi = 0; mi < 4; ++mi) {
        int row = wm * 64 + mi * 16 + lr;
        int slot = (c * 4 + lg) ^ (row & 7);
        af[mi] = *(const bf16x8*)((const char*)As + row * 128 + slot * 16);
      }
#pragma unroll
      for (int ni = 0; ni < 4; ++ni) {
        int rn = wn * 64 + ni * 16 + lr;
        int slot = (c * 4 + lg) ^ (rn & 7);
        bf16x8 bfr = *(const bf16x8*)((const char*)Bs + rn * 128 + slot * 16);
#pragma unroll
        for (int mi = 0; mi < 4; ++mi)
          acc[mi][ni] = MFMA16(af[mi], bfr, acc[mi][ni]);
      }
    }
    __syncthreads();
  }

  if (MODE == 1) {
    const float qs = 0.12755102871936672f;   // log2(e)/sqrt(128)
    if (n0 < 2560) {
      // Q or K range (block-uniform since n0 is a multiple of 128)
#pragma unroll
      for (int mi = 0; mi < 4; ++mi)
#pragma unroll
        for (int ni = 0; ni < 4; ++ni)
#pragma unroll
          for (int i = 0; i < 4; ++i) {
            float v = acc[mi][ni][i];
            float p = __shfl_xor(v, 1);      // partner of the (xr,xi) pair
            int cc = n0 + wn * 64 + ni * 16 + lr;
            int r  = m0 + wm * 64 + mi * 16 + lg * 4 + i;
            int s  = r & (S_LEN - 1);
            int j  = (cc & 127) >> 1;
            float c = fc[s * 64 + j], sn = fs[s * 64 + j];
            float o = (lr & 1) ? (p * sn + v * c)
                               : (v * c - p * sn);
            if (n0 < DMODEL) {               // Q -> xq row-major, scaled
              xq[(size_t)r * DMODEL + cc] = (__bf16)(o * qs);
            } else {                         // K -> Kp panels
              int bb = r >> 11, kt = s >> 6, rr = s & 63;
              int kvh = (cc - DMODEL) >> 7, dk = (cc - DMODEL) & 127;
              size_t e = ((size_t)((bb * 4 + kvh) * 32 + kt) * 16 + (dk >> 3)) * 512
                         + rr * 8 + (dk & 7);
              Kp[e] = (__bf16)o;
            }
          }
    } else {
      // V range -> VTp panels (no RoPE)
#pragma unroll
      for (int mi = 0; mi < 4; ++mi)
#pragma unroll
        for (int ni = 0; ni < 4; ++ni)
#pragma unroll
          for (int i = 0; i < 4; ++i) {
            float v = acc[mi][ni][i];
            int cc = n0 + wn * 64 + ni * 16 + lr;
            int r  = m0 + wm * 64 + mi * 16 + lg * 4 + i;
            int s  = r & (S_LEN - 1);
            int bb = r >> 11, kt = s >> 6, rr = s & 63;
            int kvh = (cc - 2560) >> 7, d = (cc - 2560) & 127;
            size_t e = ((size_t)((bb * 4 + kvh) * 32 + kt) * 8 + (rr >> 3)) * 1024
                       + d * 8 + (rr & 7);
            VTp[e] = (__bf16)v;
          }
    }
    return;
  }

#pragma unroll
  for (int mi = 0; mi < 4; ++mi)
#pragma unroll
    for (int ni = 0; ni < 4; ++ni)
#pragma unroll
      for (int i = 0; i < 4; ++i) {
        int r = m0 + wm * 64 + mi * 16 + lg * 4 + i;
        int cc = n0 + wn * 64 + ni * 16 + lr;
        ((float*)Cout)[(size_t)r * ldc + cc] = acc[mi][ni][i];
      }
}

// ---------------------------------------------------------------------------
// 3) Flash attention — swapped-operand 32x32 MFMA, exp2-domain softmax,
// panel-major K/V (conflict-free immediate-offset LDS reads, linear staging),
// static double-buffered K/V staging (r6 structure — proven 82 µs; the T15
// att[2] variant (r7) and KV-split (r9) both regressed and were reverted).
// ---------------------------------------------------------------------------
__global__ __launch_bounds__(256, 2) void attn_kernel(
    const __bf16* __restrict__ xq, const __bf16* __restrict__ Kp,
    const __bf16* __restrict__ VTp, __bf16* __restrict__ out) {
  __shared__ __attribute__((aligned(16))) __bf16 Ks0[64 * 128];
  __shared__ __attribute__((aligned(16))) __bf16 Ks1[64 * 128];
  __shared__ __attribute__((aligned(16))) __bf16 Vs0[128 * 64];
  __shared__ __attribute__((aligned(16))) __bf16 Vs1[128 * 64];
  const int tid = threadIdx.x;
  const int w = tid >> 6, l = tid & 63;
  const int qc = l & 31, hi = l >> 5;
  const int bh = blockIdx.y;             // 0..31
  const int b = bh >> 4, h = bh & 15, kvh = h >> 2;
  const int bkv = b * NKVH + kvh;
  const int q0 = blockIdx.x * 128 + w * 32;   // wave's first q row within S

  const __bf16* Ktiles = Kp  + (size_t)bkv * 32 * 8192;   // + kt*8192 elems
  const __bf16* Vtiles = VTp + (size_t)bkv * 32 * 8192;

  // stage one 16KB K tile + one 16KB V tile (linear copy, coalesced)
  auto stage = [&](int kt, __bf16* ksb, __bf16* vsb) {
    const __bf16* ksrc = Ktiles + (size_t)kt * 8192;
    const __bf16* vsrc = Vtiles + (size_t)kt * 8192;
#pragma unroll
    for (int t = 0; t < 4; ++t) {
      gload16(ksrc + (t * 256 + tid) * 8, (char*)ksb + t * 4096 + (w << 10));
      gload16(vsrc + (t * 256 + tid) * 8, (char*)vsb + t * 4096 + (w << 10));
    }
  };

  // Q fragments (B-operand): lane holds Q[q0+qc][d = c*16 + hi*8 + j]
  bf16x8 aq[8];
#pragma unroll
  for (int c = 0; c < 8; ++c)
    aq[c] = *(const bf16x8*)(xq + (size_t)(b * S_LEN + q0 + qc) * DMODEL +
                             h * HD_ + c * 16 + hi * 8);

  f32x16 o_acc[4] = {};                  // O^T: rows d = 32dt + crow(r,hi), col q
  float m = -1e30f, lsum = 0.0f;

  typedef union { uint32_t u[4]; bf16x8 v; } pfrag_t;

  // one kv-tile's compute (QK^T -> online softmax -> P-pack -> PV)
  auto tile_step = [&](const __bf16* ksb, const __bf16* vsb) {
    const char* kb = (const char*)ksb + hi * 1024 + qc * 16;
    const char* vb = (const char*)vsb + hi * 2048 + qc * 16;

    // ---- swapped QK^T: st[t] = S^T[kv = 32t + crow(r,hi)][q = qc] (log2-dom)
    f32x16 st[2] = {};
    __builtin_amdgcn_s_setprio(1);
#pragma unroll
    for (int t = 0; t < 2; ++t) {
#pragma unroll
      for (int c = 0; c < 8; ++c) {
        bf16x8 kf = *(const bf16x8*)(kb + c * 2048 + t * 512);
        st[t] = MFMA32(kf, aq[c], st[t]);
      }
    }
    __builtin_amdgcn_s_setprio(0);

    // ---- in-register softmax (lane owns one q row; pair lane = other half)
    float pm = st[0][0];
#pragma unroll
    for (int t = 0; t < 2; ++t)
#pragma unroll
      for (int r = 0; r < 16; ++r) pm = fmaxf(pm, st[t][r]);
    pm = fmaxf(pm, __shfl_xor(pm, 32));

    if (__any(pm - m > 11.54f)) {        // defer-max (T13), 8*log2(e)
      float mn = fmaxf(m, pm);
      float sf = fast_exp2(m - mn);
      lsum *= sf;
#pragma unroll
      for (int dt = 0; dt < 4; ++dt)
#pragma unroll
        for (int r = 0; r < 16; ++r) o_acc[dt][r] *= sf;
      m = mn;
    }

    float rsum = 0.0f;
#pragma unroll
    for (int t = 0; t < 2; ++t)
#pragma unroll
      for (int r = 0; r < 16; ++r) {
        st[t][r] = fast_exp2(st[t][r] - m);
        rsum += st[t][r];
      }
    rsum += __shfl_xor(rsum, 32);
    lsum += rsum;

    // ---- pack P -> bf16 PV fragments (cvt_pk + permlane32_swap, T12)
    pfrag_t pf[4];
#pragma unroll
    for (int t = 0; t < 2; ++t)
#pragma unroll
      for (int half = 0; half < 2; ++half) {
        int bs = half * 8;
        uint32_t x0 = cvtpk(st[t][bs + 0], st[t][bs + 1]);
        uint32_t y0 = cvtpk(st[t][bs + 4], st[t][bs + 5]);
        uint32_t x1 = cvtpk(st[t][bs + 2], st[t][bs + 3]);
        uint32_t y1 = cvtpk(st[t][bs + 6], st[t][bs + 7]);
        pswap(x0, y0);
        pswap(x1, y1);
        pf[t * 2 + half].u[0] = x0;
        pf[t * 2 + half].u[1] = x1;
        pf[t * 2 + half].u[2] = y0;
        pf[t * 2 + half].u[3] = y1;
      }

    // ---- PV transposed: O^T += mfma32(V^T_frag, P^T_frag)
    __builtin_amdgcn_s_setprio(1);
#pragma unroll
    for (int dt = 0; dt < 4; ++dt) {
#pragma unroll
      for (int ks = 0; ks < 4; ++ks) {
        bf16x8 vf = *(const bf16x8*)(vb + ks * 4096 + dt * 512);
        o_acc[dt] = MFMA32(vf, pf[ks].v, o_acc[dt]);
      }
    }
    __builtin_amdgcn_s_setprio(0);
  };

  stage(0, Ks0, Vs0);
  __syncthreads();

#pragma unroll 1
  for (int kt = 0; kt < S_LEN / 64; kt += 2) {
    stage(kt + 1, Ks1, Vs1);             // issue-early into the OTHER buffer
    tile_step(Ks0, Vs0);
    __syncthreads();                     // drain lands after full compute
    if (kt + 2 < S_LEN / 64) stage(kt + 2, Ks0, Vs0);
    tile_step(Ks1, Vs1);
    __syncthreads();
  }

  // ---- epilogue: normalize, write bf16 attn-out [b*S][H*HD]
  float rinv = 1.0f / lsum;
  const size_t orow = (size_t)(b * S_LEN + q0 + qc) * DMODEL + h * HD_;
#pragma unroll
  for (int dt = 0; dt < 4; ++dt)
#pragma unroll
    for (int rg = 0; rg < 4; ++rg) {
      bf16x4 ov;
#pragma unroll
      for (int i = 0; i < 4; ++i)
        ov[i] = (__bf16)(o_acc[dt][rg * 4 + i] * rinv);
      int d = dt * 32 + rg * 8 + hi * 4;   // crow(rg*4+i,hi) = i + 8rg + 4hi
      *(bf16x4*)(out + orow + d) = ov;
    }
}

// ---------------------------------------------------------------------------
extern "C" void kernel_launch(void* const* d_in, const int* in_sizes, int n_in,
                              void* d_out, int out_size, void* d_ws, size_t ws_size,
                              hipStream_t stream) {
  const float* x  = (const float*)d_in[0];
  const float* fc = (const float*)d_in[1];
  const float* fs = (const float*)d_in[2];
  const float* wq = (const float*)d_in[3];
  const float* wk = (const float*)d_in[4];
  const float* wv = (const float*)d_in[5];
  const float* wo = (const float*)d_in[6];
  // d_in[7]/d_in[8] caches unused (start_pos==0, s==S), d_in[9] start_pos==0.

  char* ws = (char*)d_ws;
  __bf16* xb    = (__bf16*)(ws);                 // 16 MiB: x bf16; later attn-out
  __bf16* wqkvT = (__bf16*)(ws + (16u << 20));   // 12 MiB: [3072][2048]
  __bf16* woT   = (__bf16*)(ws + (28u << 20));   //  8 MiB: [2048][2048]
  __bf16* xq    = (__bf16*)(ws + (36u << 20));   // 16 MiB: Q post-rope [4096][2048]
  __bf16* Kp    = (__bf16*)(ws + (52u << 20));   //  4 MiB: K panels
  __bf16* VTp   = (__bf16*)(ws + (56u << 20));   //  4 MiB: V^T panels

  // 1) x->bf16 + all weight transposes (one launch)
  prep_kernel<<<10752, 256, 0, stream>>>(x, xb, wq, wk, wv, wo, wqkvT, woT);
  // 2) fused QKV projection + RoPE + panel scatter -> xq / Kp / VTp
  {
    dim3 g(NQKV / 128, MROWS / 128);     // 24 x 32 = 768 blocks (768 % 8 == 0)
    gemm_kernel<1><<<g, 256, 0, stream>>>(xb, 2048, wqkvT, 2048, nullptr, 0, 2048,
                                          fc, fs, xq, Kp, VTp);
  }
  // 3) flash attention -> xb (attn-out bf16 [4096][2048])
  {
    dim3 g(S_LEN / 128, 32);
    attn_kernel<<<g, 256, 0, stream>>>(xq, Kp, VTp, xb);
  }
  // 4) output projection -> d_out f32
  {
    dim3 g(DMODEL / 128, MROWS / 128);   // 16 x 32 = 512 blocks (512 % 8 == 0)
    gemm_kernel<0><<<g, 256, 0, stream>>>(xb, 2048, woT, 2048, d_out, 2048, 2048,
                                          fc, fs, nullptr, nullptr, nullptr);
  }
}